// Round 3
// baseline (137.132 us; speedup 1.0000x reference)
//
#include <hip/hip_runtime.h>
#include <hip/hip_bf16.h>
#include <math.h>

// DETR HungarianMatcher cost matrix:
// cost[b,q,j] = 5*L1(pred_box, tgt_box) - softmax(logits)[tgt_label[j]] - 2*GIoU
// Shapes: B=16, Q=900, C=92, T=1600 -> out [B*Q, T] fp32 (92.2 MB)
//
// Round-3 structure: thread OWNS one target in registers (coords fixed for
// the whole kernel -> zero LDS traffic for boxes). Block = 320 thr covers a
// 320-target tile and loops over R=48 rows; pred box per row is read with a
// wave-uniform address -> s_load_dwordx4 (SALU, free pipe). Only LDS op in
// the hot loop is the class-prob gather s_nprob[r*96 + label].

#define NTHR 320    // 5 waves; T/NTHR = 5 tiles
#define RR   48     // rows per block; BQ/RR = 300
#define CC   92     // classes
#define CP   96     // padded class stride (96 % 32 == 0)

__global__ __launch_bounds__(NTHR) void detr_cost_kernel(
    const float* __restrict__ logits,   // [BQ, C]
    const float* __restrict__ pboxes,   // [BQ, 4] cxcywh
    const int*   __restrict__ labels,   // [T]
    const float* __restrict__ tboxes,   // [T, 4] cxcywh
    float*       __restrict__ out,      // [BQ, T]
    int T)
{
    __shared__ float s_nprob[RR * CP];  // -softmax(logits), 18.4 KB

    const int tid  = threadIdx.x;
    const int j    = blockIdx.x * NTHR + tid;  // this thread's target
    const int row0 = blockIdx.y * RR;          // base row (b*Q + q)

    // ---- own target: load once, keep in registers ----
    const float4 t = ((const float4*)tboxes)[j];   // cxcywh
    const float tx1 = t.x - 0.5f * t.z;
    const float ty1 = t.y - 0.5f * t.w;
    const float tx2 = t.x + 0.5f * t.z;
    const float ty2 = t.y + 0.5f * t.w;
    const float ta  = t.z * t.w;
    const int   lbl = labels[j];

    // ---- softmax for the block's RR rows: wave wv does rows wv, wv+5, ... ----
    const int wv = tid >> 6, ln = tid & 63;
    for (int rr = wv; rr < RR; rr += 5) {
        const float* lg = logits + (long long)(row0 + rr) * CC;
        float v1 = (ln < CC)      ? lg[ln]      : -INFINITY;
        float v2 = (ln + 64 < CC) ? lg[ln + 64] : -INFINITY;
        float m = fmaxf(v1, v2);
        #pragma unroll
        for (int o = 32; o > 0; o >>= 1) m = fmaxf(m, __shfl_xor(m, o));
        float e1 = (ln < CC)      ? __expf(v1 - m) : 0.0f;
        float e2 = (ln + 64 < CC) ? __expf(v2 - m) : 0.0f;
        float s = e1 + e2;
        #pragma unroll
        for (int o = 32; o > 0; o >>= 1) s += __shfl_xor(s, o);
        float inv = __builtin_amdgcn_rcpf(s);
        if (ln < CC)      s_nprob[rr * CP + ln]      = -e1 * inv;
        if (ln + 64 < CC) s_nprob[rr * CP + ln + 64] = -e2 * inv;
    }

    __syncthreads();

    // ---- row loop: pred box via wave-uniform (scalar) load ----
    const float4* pb4 = (const float4*)pboxes;
    #pragma unroll 4
    for (int r = 0; r < RR; ++r) {
        const float4 p = pb4[row0 + r];        // uniform addr -> s_load_dwordx4
        const float px1 = p.x - 0.5f * p.z;
        const float py1 = p.y - 0.5f * p.w;
        const float px2 = p.x + 0.5f * p.z;
        const float py2 = p.y + 0.5f * p.w;
        const float pa  = p.z * p.w;

        // class cost: the only LDS op in the hot loop
        const float nprob = s_nprob[r * CP + lbl];

        // L1 directly on cxcywh (both in regs)
        const float l1 = fabsf(p.x - t.x) + fabsf(p.y - t.y)
                       + fabsf(p.z - t.z) + fabsf(p.w - t.w);

        // IoU
        const float iw    = fminf(px2, tx2) - fmaxf(px1, tx1);
        const float ih    = fminf(py2, ty2) - fmaxf(py1, ty1);
        const float inter = fmaxf(iw, 0.0f) * fmaxf(ih, 0.0f);
        const float uni   = pa + ta - inter;
        const float iou   = inter * __builtin_amdgcn_rcpf(uni);

        // enclosing box
        const float ew   = fmaxf(px2, tx2) - fminf(px1, tx1);
        const float eh   = fmaxf(py2, ty2) - fminf(py1, ty1);
        const float ea   = ew * eh;
        const float giou = iou - (ea - uni) * __builtin_amdgcn_rcpf(ea);

        // cost = 5*L1 - prob - 2*giou   (s_nprob already holds -prob)
        out[(long long)(row0 + r) * T + j] = fmaf(5.0f, l1, nprob) - 2.0f * giou;
    }
}

extern "C" void kernel_launch(void* const* d_in, const int* in_sizes, int n_in,
                              void* d_out, int out_size, void* d_ws, size_t ws_size,
                              hipStream_t stream) {
    const float* logits = (const float*)d_in[0];   // [B,Q,C]
    const float* pboxes = (const float*)d_in[1];   // [B,Q,4]
    const int*   labels = (const int*)d_in[2];     // [T]
    const float* tboxes = (const float*)d_in[3];   // [T,4]
    float* out = (float*)d_out;

    const int T  = in_sizes[2];        // 1600
    const int BQ = in_sizes[1] / 4;    // 14400

    dim3 grid(T / NTHR, BQ / RR);      // (5, 300)
    detr_cost_kernel<<<grid, NTHR, 0, stream>>>(logits, pboxes, labels, tboxes, out, T);
}

// Round 4
// 126.410 us; speedup vs baseline: 1.0848x; 1.0848x over previous
//
#include <hip/hip_runtime.h>
#include <hip/hip_bf16.h>
#include <math.h>

// DETR HungarianMatcher cost matrix:
// cost[b,q,j] = 5*L1(pred_box, tgt_box) - softmax(logits)[tgt_label[j]] - 2*GIoU
// Shapes: B=16, Q=900, C=92, T=1600 -> out [B*Q, T] fp32 (92.2 MB)
//
// Round-4 structure:
//  - thread owns VEC=4 consecutive targets in REGISTERS (cxcywh+xyxy+area+label)
//    -> zero LDS traffic for target coords, dwordx4 stores (16 B/lane).
//  - pred rows staged ONCE in LDS (cxcywh + xyxy + area) -> per-row broadcast
//    ds_read_b128 (uniform addr, conflict-free). NO s_load in the hot loop
//    (round 3's SMEM+DS lgkmcnt mixing forced full drains each iteration).
//  - only lane-divergent LDS op: class-prob gather s_nprob[r*96 + label].

#define NTHR 256            // 4 waves
#define VEC  4              // targets per thread
#define TILE (NTHR * VEC)   // 1024 targets per block (grid.x = 2, guarded)
#define RR   16             // rows per block; grid.y = BQ/RR = 900
#define CC   92             // classes
#define CP   96             // padded class stride

__global__ __launch_bounds__(NTHR) void detr_cost_kernel(
    const float* __restrict__ logits,   // [BQ, C]
    const float* __restrict__ pboxes,   // [BQ, 4] cxcywh
    const int*   __restrict__ labels,   // [T]
    const float* __restrict__ tboxes,   // [T, 4] cxcywh
    float*       __restrict__ out,      // [BQ, T]
    int T)
{
    __shared__ float  s_nprob[RR * CP]; // -softmax per row (6.1 KB)
    __shared__ float4 s_pc[RR];         // pred cxcywh
    __shared__ float4 s_px[RR];         // pred xyxy
    __shared__ float  s_pa[RR];         // pred area

    const int tid  = threadIdx.x;
    const int j0   = blockIdx.x * TILE + tid * VEC;  // first owned target
    const int row0 = blockIdx.y * RR;
    const bool active = (j0 + VEC - 1) < T;

    // ---- own targets: load once into registers ----
    float tcx[VEC], tcy[VEC], tw[VEC], th[VEC];
    float tx1[VEC], ty1[VEC], tx2[VEC], ty2[VEC], ta[VEC];
    int   lbl[VEC];
    if (active) {
        const float4* tb4 = (const float4*)tboxes;
        const int4 lb = *(const int4*)(labels + j0);
        const int* lp = (const int*)&lb;
        #pragma unroll
        for (int u = 0; u < VEC; ++u) {
            float4 t = tb4[j0 + u];
            tcx[u] = t.x; tcy[u] = t.y; tw[u] = t.z; th[u] = t.w;
            tx1[u] = t.x - 0.5f * t.z;
            ty1[u] = t.y - 0.5f * t.w;
            tx2[u] = t.x + 0.5f * t.z;
            ty2[u] = t.y + 0.5f * t.w;
            ta[u]  = t.z * t.w;
            lbl[u] = lp[u];
        }
    }

    // ---- stage pred rows: cxcywh + xyxy + area ----
    if (tid < RR) {
        float4 p = ((const float4*)pboxes)[row0 + tid];
        float x1 = p.x - 0.5f * p.z, y1 = p.y - 0.5f * p.w;
        float x2 = p.x + 0.5f * p.z, y2 = p.y + 0.5f * p.w;
        s_pc[tid] = p;
        s_px[tid] = make_float4(x1, y1, x2, y2);
        s_pa[tid] = p.z * p.w;
    }

    // ---- softmax: wave wv handles rows wv, wv+4, ... ----
    const int wv = tid >> 6, ln = tid & 63;
    for (int rr = wv; rr < RR; rr += 4) {
        const float* lg = logits + (long long)(row0 + rr) * CC;
        float v1 = (ln < CC)      ? lg[ln]      : -INFINITY;
        float v2 = (ln + 64 < CC) ? lg[ln + 64] : -INFINITY;
        float m = fmaxf(v1, v2);
        #pragma unroll
        for (int o = 32; o > 0; o >>= 1) m = fmaxf(m, __shfl_xor(m, o));
        float e1 = (ln < CC)      ? __expf(v1 - m) : 0.0f;
        float e2 = (ln + 64 < CC) ? __expf(v2 - m) : 0.0f;
        float s = e1 + e2;
        #pragma unroll
        for (int o = 32; o > 0; o >>= 1) s += __shfl_xor(s, o);
        float inv = __builtin_amdgcn_rcpf(s);
        if (ln < CC)      s_nprob[rr * CP + ln]      = -e1 * inv;
        if (ln + 64 < CC) s_nprob[rr * CP + ln + 64] = -e2 * inv;
    }

    __syncthreads();
    if (!active) return;   // block 2's tail waves retire here

    // ---- row loop: all LDS, no SMEM; dwordx4 stores ----
    float* outp = out + (long long)row0 * T + j0;
    #pragma unroll 2
    for (int r = 0; r < RR; ++r) {
        const float4 pc = s_pc[r];       // broadcast b128
        const float4 px = s_px[r];       // broadcast b128
        const float  pa = s_pa[r];
        const float* np = &s_nprob[r * CP];

        float4 res;
        float* rp = (float*)&res;
        #pragma unroll
        for (int u = 0; u < VEC; ++u) {
            // L1 on cxcywh (abs folds into modifier)
            const float l1 = fabsf(pc.x - tcx[u]) + fabsf(pc.y - tcy[u])
                           + fabsf(pc.z - tw[u])  + fabsf(pc.w - th[u]);

            // IoU
            const float iw    = fminf(px.z, tx2[u]) - fmaxf(px.x, tx1[u]);
            const float ih    = fminf(px.w, ty2[u]) - fmaxf(px.y, ty1[u]);
            const float inter = fmaxf(iw, 0.0f) * fmaxf(ih, 0.0f);
            const float uni   = pa + ta[u] - inter;
            const float iou   = inter * __builtin_amdgcn_rcpf(uni);

            // enclosing box
            const float ew   = fmaxf(px.z, tx2[u]) - fminf(px.x, tx1[u]);
            const float eh   = fmaxf(px.w, ty2[u]) - fminf(px.y, ty1[u]);
            const float ea   = ew * eh;
            const float giou = iou - (ea - uni) * __builtin_amdgcn_rcpf(ea);

            // cost = 5*L1 - prob - 2*giou   (s_nprob holds -prob)
            rp[u] = fmaf(5.0f, l1, np[lbl[u]]) - 2.0f * giou;
        }
        *(float4*)(outp + (long long)r * T) = res;
    }
}

extern "C" void kernel_launch(void* const* d_in, const int* in_sizes, int n_in,
                              void* d_out, int out_size, void* d_ws, size_t ws_size,
                              hipStream_t stream) {
    const float* logits = (const float*)d_in[0];   // [B,Q,C]
    const float* pboxes = (const float*)d_in[1];   // [B,Q,4]
    const int*   labels = (const int*)d_in[2];     // [T]
    const float* tboxes = (const float*)d_in[3];   // [T,4]
    float* out = (float*)d_out;

    const int T  = in_sizes[2];        // 1600
    const int BQ = in_sizes[1] / 4;    // 14400

    dim3 grid((T + TILE - 1) / TILE, BQ / RR);   // (2, 900)
    detr_cost_kernel<<<grid, NTHR, 0, stream>>>(logits, pboxes, labels, tboxes, out, T);
}